// Round 3
// baseline (453.923 us; speedup 1.0000x reference)
//
#include <hip/hip_runtime.h>

#define H_IMG 1024
#define W_IMG 1024
#define N_IMG 16
#define C_IMG 3
#define PPT   4   // pixels per thread (16B store)

typedef float vfloat4 __attribute__((ext_vector_type(4)));  // clang-native, OK for nontemporal builtin

__global__ __launch_bounds__(256) void homography_warp_kernel(
    const float* __restrict__ img,   // [N, 3, H, W]
    const float* __restrict__ homo,  // [N, 3, 3]
    float* __restrict__ out)         // [N, 3, H, W]
{
    const int n    = blockIdx.y;
    const int pix0 = (blockIdx.x * 256 + threadIdx.x) * PPT;  // first pixel of this thread
    const int h    = pix0 >> 10;                              // W_IMG == 1024
    const int w0   = pix0 & (W_IMG - 1);                      // PPT=4 divides 1024 -> same row

    // Block-uniform homography coefficients (blockIdx.y-indexed -> scalar loads)
    const float* Hm = homo + n * 9;
    const float h00 = Hm[0], h01 = Hm[1], h02 = Hm[2];
    const float h10 = Hm[3], h11 = Hm[4], h12 = Hm[5];
    const float h20 = Hm[6], h21 = Hm[7], h22 = Hm[8];

    const float gy = fmaf((float)h, 2.0f / (H_IMG - 1), -1.0f);
    // gy-dependent partials (gx varies per pixel)
    const float cx = fmaf(h01, gy, h02);
    const float cy = fmaf(h11, gy, h12);
    const float cz = fmaf(h21, gy, h22);

    // Per-pixel gather offsets + bilinear weights (unrolled -> registers)
    int   off[PPT][4];
    float wt [PPT][4];
#pragma unroll
    for (int i = 0; i < PPT; ++i) {
        const float gx = fmaf((float)(w0 + i), 2.0f / (W_IMG - 1), -1.0f);

        const float tx = fmaf(h00, gx, cx);
        const float ty = fmaf(h10, gx, cy);
        const float tz = fmaf(h20, gx, cz);
        const float inv = 1.0f / tz;            // accurate fp32 division (no fast-math)
        const float u = tx * inv;
        const float v = ty * inv;

        // Map to pixel coords (align_corners=True)
        const float xp = (u + 1.0f) * 0.5f * (float)(W_IMG - 1);
        const float yp = (v + 1.0f) * 0.5f * (float)(H_IMG - 1);

        const float x0f = floorf(xp);
        const float y0f = floorf(yp);
        const float fx = xp - x0f;
        const float fy = yp - y0f;

        const int ix0 = (int)x0f;
        const int iy0 = (int)y0f;
        const int ix1 = ix0 + 1;
        const int iy1 = iy0 + 1;

        // zeros-padding validity per corner, folded into the bilinear weights
        const float vx0 = (ix0 >= 0 && ix0 < W_IMG) ? 1.0f : 0.0f;
        const float vx1 = (ix1 >= 0 && ix1 < W_IMG) ? 1.0f : 0.0f;
        const float vy0 = (iy0 >= 0 && iy0 < H_IMG) ? 1.0f : 0.0f;
        const float vy1 = (iy1 >= 0 && iy1 < H_IMG) ? 1.0f : 0.0f;

        wt[i][0] = (1.0f - fx) * (1.0f - fy) * vx0 * vy0;
        wt[i][1] = fx * (1.0f - fy) * vx1 * vy0;
        wt[i][2] = (1.0f - fx) * fy * vx0 * vy1;
        wt[i][3] = fx * fy * vx1 * vy1;

        // Clipped gather indices (OOB lanes have weight 0 anyway)
        const int cx0 = min(max(ix0, 0), W_IMG - 1);
        const int cx1 = min(max(ix1, 0), W_IMG - 1);
        const int cy0 = min(max(iy0, 0), H_IMG - 1);
        const int cy1 = min(max(iy1, 0), H_IMG - 1);

        off[i][0] = cy0 * W_IMG + cx0;
        off[i][1] = cy0 * W_IMG + cx1;
        off[i][2] = cy1 * W_IMG + cx0;
        off[i][3] = cy1 * W_IMG + cx1;
    }

    const size_t plane = (size_t)H_IMG * W_IMG;
    const size_t base  = (size_t)n * C_IMG * plane;

#pragma unroll
    for (int c = 0; c < C_IMG; ++c) {
        const float* p = img + base + (size_t)c * plane;

        // Issue all 16 gathers for this channel, then reduce (max MLP).
        float v00[PPT], v01[PPT], v10[PPT], v11[PPT];
#pragma unroll
        for (int i = 0; i < PPT; ++i) {
            v00[i] = p[off[i][0]];
            v01[i] = p[off[i][1]];
            v10[i] = p[off[i][2]];
            v11[i] = p[off[i][3]];
        }

        vfloat4 r;
#pragma unroll
        for (int i = 0; i < PPT; ++i) {
            r[i] = wt[i][0] * v00[i] + wt[i][1] * v01[i]
                 + wt[i][2] * v10[i] + wt[i][3] * v11[i];
        }

        // Streaming output: nontemporal so the 201 MB write stream doesn't
        // evict gather lines from L2.
        vfloat4* dst = (vfloat4*)(out + base + (size_t)c * plane + (size_t)pix0);
        __builtin_nontemporal_store(r, dst);
    }
}

extern "C" void kernel_launch(void* const* d_in, const int* in_sizes, int n_in,
                              void* d_out, int out_size, void* d_ws, size_t ws_size,
                              hipStream_t stream) {
    const float* img  = (const float*)d_in[0];   // patch_src    [16,3,1024,1024]
    const float* homo = (const float*)d_in[1];   // dst_homo_src [16,3,3]
    float* out = (float*)d_out;                  // [16,3,1024,1024] fp32

    dim3 block(256);
    dim3 grid((H_IMG * W_IMG) / (256 * PPT), N_IMG);
    homography_warp_kernel<<<grid, block, 0, stream>>>(img, homo, out);
}

// Round 4
// 378.585 us; speedup vs baseline: 1.1990x; 1.1990x over previous
//
#include <hip/hip_runtime.h>

#define H_IMG 1024
#define W_IMG 1024
#define N_IMG 16
#define C_IMG 3

// 2nd arg (min waves/EU = 4) lets the allocator use up to 128 VGPRs and
// biases the scheduler toward hoisting independent loads (MLP) instead of
// minimizing registers. Round 0/3 without it: VGPR=16/32, loads serialized.
__global__ __launch_bounds__(256, 4) void homography_warp_kernel(
    const float* __restrict__ img,   // [N, 3, H, W]
    const float* __restrict__ homo,  // [N, 3, 3]
    float* __restrict__ out)         // [N, 3, H, W]
{
    const int n   = blockIdx.y;
    const int pix = blockIdx.x * 256 + threadIdx.x;   // pixel index within image
    const int h   = pix >> 10;                         // W_IMG == 1024
    const int w   = pix & (W_IMG - 1);

    // Block-uniform homography coefficients (blockIdx.y-indexed -> scalar loads)
    const float* Hm = homo + n * 9;
    const float h00 = Hm[0], h01 = Hm[1], h02 = Hm[2];
    const float h10 = Hm[3], h11 = Hm[4], h12 = Hm[5];
    const float h20 = Hm[6], h21 = Hm[7], h22 = Hm[8];

    // Normalized meshgrid coords in [-1, 1] (matches jnp.linspace endpoints)
    const float gx = fmaf((float)w, 2.0f / (W_IMG - 1), -1.0f);
    const float gy = fmaf((float)h, 2.0f / (H_IMG - 1), -1.0f);

    // Homogeneous transform
    const float tx = fmaf(h00, gx, fmaf(h01, gy, h02));
    const float ty = fmaf(h10, gx, fmaf(h11, gy, h12));
    const float tz = fmaf(h20, gx, fmaf(h21, gy, h22));
    const float inv = 1.0f / tz;   // accurate fp32 division (no fast-math)
    const float u = tx * inv;
    const float v = ty * inv;

    // Map to pixel coords (align_corners=True)
    const float xp = (u + 1.0f) * 0.5f * (float)(W_IMG - 1);
    const float yp = (v + 1.0f) * 0.5f * (float)(H_IMG - 1);

    const float x0f = floorf(xp);
    const float y0f = floorf(yp);
    const float fx = xp - x0f;
    const float fy = yp - y0f;

    const int ix0 = (int)x0f;
    const int iy0 = (int)y0f;
    const int ix1 = ix0 + 1;
    const int iy1 = iy0 + 1;

    // zeros-padding validity per corner, folded into the bilinear weights
    const float vx0 = (ix0 >= 0 && ix0 < W_IMG) ? 1.0f : 0.0f;
    const float vx1 = (ix1 >= 0 && ix1 < W_IMG) ? 1.0f : 0.0f;
    const float vy0 = (iy0 >= 0 && iy0 < H_IMG) ? 1.0f : 0.0f;
    const float vy1 = (iy1 >= 0 && iy1 < H_IMG) ? 1.0f : 0.0f;

    const float w00 = (1.0f - fx) * (1.0f - fy) * vx0 * vy0;
    const float w01 = fx * (1.0f - fy) * vx1 * vy0;
    const float w10 = (1.0f - fx) * fy * vx0 * vy1;
    const float w11 = fx * fy * vx1 * vy1;

    // Clipped gather indices (OOB lanes have weight 0 anyway)
    const int cx0 = min(max(ix0, 0), W_IMG - 1);
    const int cx1 = min(max(ix1, 0), W_IMG - 1);
    const int cy0 = min(max(iy0, 0), H_IMG - 1);
    const int cy1 = min(max(iy1, 0), H_IMG - 1);

    const int o00 = cy0 * W_IMG + cx0;
    const int o01 = cy0 * W_IMG + cx1;
    const int o10 = cy1 * W_IMG + cx0;
    const int o11 = cy1 * W_IMG + cx1;

    const size_t plane = (size_t)H_IMG * W_IMG;
    const size_t base  = (size_t)n * C_IMG * plane;

    // Block-uniform plane bases (SGPR) + 4 per-lane offsets (VGPR):
    // issue ALL 12 gathers before any arithmetic so they share one long
    // vmcnt window instead of 3 serial 4-load batches.
    const float* p0 = img + base;            // c = 0
    const float* p1 = p0 + plane;            // c = 1
    const float* p2 = p1 + plane;            // c = 2

    float g00_0 = p0[o00], g01_0 = p0[o01], g10_0 = p0[o10], g11_0 = p0[o11];
    float g00_1 = p1[o00], g01_1 = p1[o01], g10_1 = p1[o10], g11_1 = p1[o11];
    float g00_2 = p2[o00], g01_2 = p2[o01], g10_2 = p2[o10], g11_2 = p2[o11];

    const float r0 = w00 * g00_0 + w01 * g01_0 + w10 * g10_0 + w11 * g11_0;
    const float r1 = w00 * g00_1 + w01 * g01_1 + w10 * g10_1 + w11 * g11_1;
    const float r2 = w00 * g00_2 + w01 * g01_2 + w10 * g10_2 + w11 * g11_2;

    out[base + (size_t)pix]             = r0;
    out[base + plane + (size_t)pix]     = r1;
    out[base + 2 * plane + (size_t)pix] = r2;
}

extern "C" void kernel_launch(void* const* d_in, const int* in_sizes, int n_in,
                              void* d_out, int out_size, void* d_ws, size_t ws_size,
                              hipStream_t stream) {
    const float* img  = (const float*)d_in[0];   // patch_src    [16,3,1024,1024]
    const float* homo = (const float*)d_in[1];   // dst_homo_src [16,3,3]
    float* out = (float*)d_out;                  // [16,3,1024,1024] fp32

    dim3 block(256);
    dim3 grid((H_IMG * W_IMG) / 256, N_IMG);
    homography_warp_kernel<<<grid, block, 0, stream>>>(img, homo, out);
}

// Round 5
// 347.292 us; speedup vs baseline: 1.3070x; 1.0901x over previous
//
#include <hip/hip_runtime.h>

#define H_IMG 1024
#define W_IMG 1024
#define N_IMG 16
#define C_IMG 3

typedef float f2 __attribute__((ext_vector_type(2)));

__global__ __launch_bounds__(256) void homography_warp_kernel(
    const float* __restrict__ img,   // [N, 3, H, W]
    const float* __restrict__ homo,  // [N, 3, 3]
    float* __restrict__ out)         // [N, 3, H, W]
{
    const int n   = blockIdx.y;
    const int pix = blockIdx.x * 256 + threadIdx.x;   // pixel index within image
    const int h   = pix >> 10;                         // W_IMG == 1024
    const int w   = pix & (W_IMG - 1);

    // Block-uniform homography coefficients (blockIdx.y-indexed -> scalar loads)
    const float* Hm = homo + n * 9;
    const float h00 = Hm[0], h01 = Hm[1], h02 = Hm[2];
    const float h10 = Hm[3], h11 = Hm[4], h12 = Hm[5];
    const float h20 = Hm[6], h21 = Hm[7], h22 = Hm[8];

    // Normalized meshgrid coords in [-1, 1] (matches jnp.linspace endpoints)
    const float gx = fmaf((float)w, 2.0f / (W_IMG - 1), -1.0f);
    const float gy = fmaf((float)h, 2.0f / (H_IMG - 1), -1.0f);

    // Homogeneous transform
    const float tx = fmaf(h00, gx, fmaf(h01, gy, h02));
    const float ty = fmaf(h10, gx, fmaf(h11, gy, h12));
    const float tz = fmaf(h20, gx, fmaf(h21, gy, h22));
    const float inv = 1.0f / tz;   // accurate fp32 division (no fast-math)
    const float u = tx * inv;
    const float v = ty * inv;

    // Map to pixel coords (align_corners=True)
    const float xp = (u + 1.0f) * 0.5f * (float)(W_IMG - 1);
    const float yp = (v + 1.0f) * 0.5f * (float)(H_IMG - 1);

    const float x0f = floorf(xp);
    const float y0f = floorf(yp);
    const float fx = xp - x0f;
    const float fy = yp - y0f;

    const int ix0 = (int)x0f;
    const int iy0 = (int)y0f;
    const int ix1 = ix0 + 1;
    const int iy1 = iy0 + 1;

    // zeros-padding validity per corner, folded into the bilinear weights
    const float vx0 = (ix0 >= 0 && ix0 < W_IMG) ? 1.0f : 0.0f;
    const float vx1 = (ix1 >= 0 && ix1 < W_IMG) ? 1.0f : 0.0f;
    const float vy0 = (iy0 >= 0 && iy0 < H_IMG) ? 1.0f : 0.0f;
    const float vy1 = (iy1 >= 0 && iy1 < H_IMG) ? 1.0f : 0.0f;

    const float w00 = (1.0f - fx) * (1.0f - fy) * vx0 * vy0;
    const float w01 = fx * (1.0f - fy) * vx1 * vy0;
    const float w10 = (1.0f - fx) * fy * vx0 * vy1;
    const float w11 = fx * fy * vx1 * vy1;

    // --- paired-corner gathers: one dwordx2 per (row, channel) -------------
    // x0/x1 are adjacent columns; load the pair at pbx = clamp(ix0, 0, W-2)
    // and pre-select which half each weight applies to. OOB corners have
    // weight 0, so the selects are exact at the edges.
    const int  pbx    = min(max(ix0, 0), W_IMG - 2);
    const bool selhi0 = (ix0 > pbx);   // x0 lives in .y (only at right edge / OOB)
    const bool selhi1 = (ix0 >= 0);    // x1 lives in .y (common case)

    // lo/hi pair weights per row (shared across channels)
    const float wl0 = (selhi0 ? 0.0f : w00) + (selhi1 ? 0.0f : w01);
    const float wh0 = (selhi0 ? w00 : 0.0f) + (selhi1 ? w01 : 0.0f);
    const float wl1 = (selhi0 ? 0.0f : w10) + (selhi1 ? 0.0f : w11);
    const float wh1 = (selhi0 ? w10 : 0.0f) + (selhi1 ? w11 : 0.0f);

    const int cy0 = min(max(iy0, 0), H_IMG - 1);
    const int cy1 = min(max(iy1, 0), H_IMG - 1);

    const int o0 = cy0 * W_IMG + pbx;   // element offset of the y0-row pair
    const int o1 = cy1 * W_IMG + pbx;   // element offset of the y1-row pair

    const size_t plane = (size_t)H_IMG * W_IMG;
    const size_t base  = (size_t)n * C_IMG * plane;

    const float* p0 = img + base;        // c = 0
    const float* p1 = p0 + plane;        // c = 1
    const float* p2 = p1 + plane;        // c = 2

    // Issue all 6 paired gathers before any consumption (max MLP, half the
    // VMEM instructions and roughly half the L1 line-transactions of the
    // 12-scalar-gather version).
    f2 a0, b0, a1, b1, a2, b2;
    __builtin_memcpy(&a0, p0 + o0, 8);
    __builtin_memcpy(&b0, p0 + o1, 8);
    __builtin_memcpy(&a1, p1 + o0, 8);
    __builtin_memcpy(&b1, p1 + o1, 8);
    __builtin_memcpy(&a2, p2 + o0, 8);
    __builtin_memcpy(&b2, p2 + o1, 8);

    const float r0 = wl0 * a0.x + wh0 * a0.y + wl1 * b0.x + wh1 * b0.y;
    const float r1 = wl0 * a1.x + wh0 * a1.y + wl1 * b1.x + wh1 * b1.y;
    const float r2 = wl0 * a2.x + wh0 * a2.y + wl1 * b2.x + wh1 * b2.y;

    out[base + (size_t)pix]             = r0;
    out[base + plane + (size_t)pix]     = r1;
    out[base + 2 * plane + (size_t)pix] = r2;
}

extern "C" void kernel_launch(void* const* d_in, const int* in_sizes, int n_in,
                              void* d_out, int out_size, void* d_ws, size_t ws_size,
                              hipStream_t stream) {
    const float* img  = (const float*)d_in[0];   // patch_src    [16,3,1024,1024]
    const float* homo = (const float*)d_in[1];   // dst_homo_src [16,3,3]
    float* out = (float*)d_out;                  // [16,3,1024,1024] fp32

    dim3 block(256);
    dim3 grid((H_IMG * W_IMG) / 256, N_IMG);
    homography_warp_kernel<<<grid, block, 0, stream>>>(img, homo, out);
}